// Round 7
// baseline (3002.698 us; speedup 1.0000x reference)
//
#include <hip/hip_runtime.h>

#define T_LEN 16384
#define HDIM 64
#define BATCH 64

// K = DELAY / OS_FACTOR = 1/1.5 = 2/3
#define KBLEND      (2.0f / 3.0f)
#define ONE_MINUS_K (1.0f / 3.0f)
#define KK          (KBLEND * ONE_MINUS_K)     // K*(1-K)

// tanh(x) = 1 - 2/(1 + exp2(C2*x)); C2 = 2*log2(e). Exact algebra, 5-dep chain.
#define C2    2.8853900817779268f
#define C2K   (C2 * KBLEND)
#define C2KK  (C2 * KK)

typedef _Float16 h2 __attribute__((ext_vector_type(2)));

__device__ __forceinline__ float lane_bcast(float v, int lane) {
    return __int_as_float(__builtin_amdgcn_readlane(__float_as_int(v), lane));
}

// waves_per_eu(1,1): 512-VGPR budget -> weight row register-resident
// (round 4: 56->132 VGPRs, 5585->3113 us).
__global__ __launch_bounds__(HDIM)
__attribute__((amdgpu_waves_per_eu(1, 1)))
void rnn_delayline_kernel(
    const float* __restrict__ x,      // [B, T, 1]
    const float* __restrict__ Wih,    // [H, 1]
    const float* __restrict__ Whh,    // [H, H] row-major
    const float* __restrict__ bih,    // [H]
    const float* __restrict__ bhh,    // [H]
    float* __restrict__ out_states,   // [B, T, H]
    float* __restrict__ out_hlast)    // [B, H]
{
    const int lane = threadIdx.x;   // h index, 0..63 (one wave per block)
    const int b    = blockIdx.x;    // batch index

    // This lane's W_hh row as 32 packed f16 pairs (for v_dot2_f32_f16).
    h2 w2h[32];
    {
        const float4* wrow = reinterpret_cast<const float4*>(Whh + lane * HDIM);
        #pragma unroll
        for (int kk = 0; kk < 16; ++kk) {
            float4 v = wrow[kk];
            w2h[2*kk+0] = (h2){(_Float16)v.x, (_Float16)v.y};
            w2h[2*kk+1] = (h2){(_Float16)v.z, (_Float16)v.w};
        }
    }

    const float wihC2  = C2 * Wih[lane];
    const float biasC2 = C2 * (bih[lane] + bhh[lane]);

    // State: dot = W·cell_{t-1}; G = C2*(1-K)*d_{t-2} with d_t = W·h_t; h off-chain.
    float h = 0.0f, dot = 0.0f, G = 0.0f;

    const float* xb = x + (size_t)b * T_LEN;
    float xcur = xb[lane];          // 64 timesteps of x per chunk, one per lane

    float* outp = out_states + ((size_t)b * T_LEN) * HDIM + lane;

    const int NCHUNK = T_LEN / HDIM;   // 256
    for (int c = 0; c < NCHUNK; ++c) {
        float xnext = 0.0f;
        if (c + 1 < NCHUNK) xnext = xb[(size_t)(c + 1) * HDIM + lane];

        #pragma unroll 4
        for (int tt = 0; tt < HDIM; ++tt) {
            // In-loop pin: weights are loop-carried asm outputs -> must stay
            // register-resident (zero instructions emitted).
            asm volatile("" : "+v"(w2h[0]), "+v"(w2h[1]), "+v"(w2h[2]), "+v"(w2h[3]),
                              "+v"(w2h[4]), "+v"(w2h[5]), "+v"(w2h[6]), "+v"(w2h[7]));
            asm volatile("" : "+v"(w2h[8]), "+v"(w2h[9]), "+v"(w2h[10]), "+v"(w2h[11]),
                              "+v"(w2h[12]), "+v"(w2h[13]), "+v"(w2h[14]), "+v"(w2h[15]));
            asm volatile("" : "+v"(w2h[16]), "+v"(w2h[17]), "+v"(w2h[18]), "+v"(w2h[19]),
                              "+v"(w2h[20]), "+v"(w2h[21]), "+v"(w2h[22]), "+v"(w2h[23]));
            asm volatile("" : "+v"(w2h[24]), "+v"(w2h[25]), "+v"(w2h[26]), "+v"(w2h[27]),
                              "+v"(w2h[28]), "+v"(w2h[29]), "+v"(w2h[30]), "+v"(w2h[31]));

            // ---- off-chain inputs (ready before dot arrives) ----
            float xt     = lane_bcast(xcur, tt);      // x_t (I=1: same for all h)
            float xpreC2 = fmaf(xt, wihC2, biasC2);   // C2*(x*W_ih + bias)
            float cb     = xpreC2 + G;                // C2*(xpre + (1-K)*d_{t-2})

            // ---- critical chain: fma -> exp2 -> add -> rcp -> fma ----
            float targ = fmaf(C2K, dot, cb);          // C2 * arg
            float e    = __builtin_amdgcn_exp2f(targ);
            float r    = __builtin_amdgcn_rcpf(1.0f + e);
            float cell = fmaf(-2.0f, r, 1.0f);        // tanh(arg), exact algebra

            // ---- pair neighbor cells, pack to f16 (even lanes hold (c2i,c2i+1))
            int ci  = __float_as_int(cell);
            int ni  = __builtin_amdgcn_update_dpp(0, ci, 0xB1, 0xF, 0xF, true); // quad_perm [1,0,3,2]
            int pki = __builtin_bit_cast(int,
                          __builtin_amdgcn_cvt_pkrtz(cell, __int_as_float(ni)));

            // ---- off-chain state updates (overlap the gather) ----
            G = fmaf(ONE_MINUS_K, G, C2KK * dot);     // C2*((1-K)g + K(1-K)dot)
            float hpre = ONE_MINUS_K * h;
            h = fmaf(KBLEND, cell, hpre);             // h = (1-K)h + K*cell
            *outp = h;                                // coalesced 256B/wave store
            outp += HDIM;

            // ---- matvec via SGPR broadcast: 32 readlane + 32 fdot2 ----
            // cell pairs are wave-uniform -> VOP3P takes them as the SGPR
            // operand; no LDS write/read (~180 cyc) on the chain at all.
            float acc[8];
            #pragma unroll
            for (int i = 0; i < 32; ++i) {
                int si   = __builtin_amdgcn_readlane(pki, 2 * i);
                h2 cpair = __builtin_bit_cast(h2, si);
                if (i < 8) {
                    acc[i] = __builtin_amdgcn_fdot2(w2h[i], cpair, 0.0f, false);
                } else {
                    acc[i & 7] = __builtin_amdgcn_fdot2(w2h[i], cpair, acc[i & 7], false);
                }
            }
            float s01 = acc[0] + acc[1], s23 = acc[2] + acc[3];
            float s45 = acc[4] + acc[5], s67 = acc[6] + acc[7];
            dot = (s01 + s23) + (s45 + s67);          // dot_t
        }

        xcur = xnext;   // rotate x chunk (register, no LDS)
    }

    out_hlast[b * HDIM + lane] = h;
}

extern "C" void kernel_launch(void* const* d_in, const int* in_sizes, int n_in,
                              void* d_out, int out_size, void* d_ws, size_t ws_size,
                              hipStream_t stream) {
    const float* x   = (const float*)d_in[0];
    const float* Wih = (const float*)d_in[1];
    const float* Whh = (const float*)d_in[2];
    const float* bih = (const float*)d_in[3];
    const float* bhh = (const float*)d_in[4];

    float* out_states = (float*)d_out;
    float* out_hlast  = out_states + (size_t)BATCH * T_LEN * HDIM;

    rnn_delayline_kernel<<<dim3(BATCH), dim3(HDIM), 0, stream>>>(
        x, Wih, Whh, bih, bhh, out_states, out_hlast);
}

// Round 10
// 2398.321 us; speedup vs baseline: 1.2520x; 1.2520x over previous
//
#include <hip/hip_runtime.h>

#define T_LEN 16384
#define HDIM 64
#define BATCH 64

// K = DELAY / OS_FACTOR = 1/1.5 = 2/3
#define KBLEND      (2.0f / 3.0f)
#define ONE_MINUS_K (1.0f / 3.0f)
#define KK          (KBLEND * ONE_MINUS_K)

// tanh(x) = 1 - 2/(1 + exp2(C2*x)); C2 = 2*log2(e). Exact algebra.
#define C2    2.8853900817779268f
#define C2K   (C2 * KBLEND)
#define C2KK  (C2 * KK)

typedef _Float16 f16x8 __attribute__((ext_vector_type(8)));
typedef float    f32x4 __attribute__((ext_vector_type(4)));

__device__ __forceinline__ float lane_bcast(float v, int lane) {
    return __int_as_float(__builtin_amdgcn_readlane(__float_as_int(v), lane));
}

// waves_per_eu(1,1): 512-VGPR budget -> weight frags stay register-resident
// (round 4 evidence: 56->132 VGPRs, 5585->3113 us).
__global__ __launch_bounds__(HDIM)
__attribute__((amdgpu_waves_per_eu(1, 1)))
void rnn_delayline_kernel(
    const float* __restrict__ x,      // [B, T, 1]
    const float* __restrict__ Wih,    // [H, 1]
    const float* __restrict__ Whh,    // [H, H] row-major
    const float* __restrict__ bih,    // [H]
    const float* __restrict__ bhh,    // [H]
    float* __restrict__ out_states,   // [B, T, H]
    float* __restrict__ out_hlast)    // [B, H]
{
    const int lane = threadIdx.x;   // h index, 0..63 (one wave per block)
    const int b    = blockIdx.x;    // batch index

    __shared__ __align__(16) _Float16 hbuf[HDIM];   // f16 cell buffer (128 B)

    const float* xb = x + (size_t)b * T_LEN;

    // ---- B fragments: W^T chunks for mfma_f32_16x16x32_f16 ----
    // D_j = A_s · B[j][s] summed over s; D_j[m][n] = dot[j*16+n] (A row-replicated).
    // Assumed B layout: lane l holds B[k=(l>>4)*8+i][n=l&15]
    //   => B[j][s][i] = W[j*16 + (l&15)][s*32 + (l>>4)*8 + i]
    f16x8 Bf[8];   // [j*2 + s]
    {
        const int n = lane & 15, g = lane >> 4;
        #pragma unroll
        for (int j = 0; j < 4; ++j) {
            const float* wrow = Whh + (j * 16 + n) * HDIM;
            #pragma unroll
            for (int s = 0; s < 2; ++s) {
                const float4* wp = reinterpret_cast<const float4*>(wrow + s * 32 + g * 8);
                float4 v0 = wp[0], v1 = wp[1];
                Bf[j*2+s] = (f16x8){(_Float16)v0.x, (_Float16)v0.y,
                                    (_Float16)v0.z, (_Float16)v0.w,
                                    (_Float16)v1.x, (_Float16)v1.y,
                                    (_Float16)v1.z, (_Float16)v1.w};
            }
        }
    }

    const float wihC2  = C2 * Wih[lane];
    const float biasC2 = C2 * (bih[lane] + bhh[lane]);

    // Per-lane A-gather addresses: lane l needs c[(l>>4)*8 + i] (k-tile 0)
    // and c[32 + (l>>4)*8 + i] (k-tile 1) -> 16B each, 4 distinct chunks/wave.
    const char* hbB = reinterpret_cast<const char*>(hbuf);
    const int   gofs = (lane >> 4) * 16;

    // D->dot select: lane l takes D_{l>>4}[0] (all rows of D_j are identical).
    const bool selLo = ((lane >> 4) & 1) != 0;
    const bool selHi = ((lane >> 4) & 2) != 0;

    // State: dot = W·cell_{t-1}; G = C2*(1-K)*d_{t-2} with d_t = W·h_t.
    float h = 0.0f, dot = 0.0f, G = 0.0f;

    float xcur = xb[lane];          // 64 timesteps of x per chunk, one per lane
    float* outp = out_states + (size_t)b * T_LEN * HDIM + lane;

    const int NCHUNK = T_LEN / HDIM;   // 256
    for (int c = 0; c < NCHUNK; ++c) {
        float xnext = 0.0f;
        if (c + 1 < NCHUNK) xnext = xb[(size_t)(c + 1) * HDIM + lane];

        #pragma unroll 4
        for (int tt = 0; tt < HDIM; ++tt) {
            // In-loop pin: weight frags are loop-carried asm outputs -> resident.
            asm volatile("" : "+v"(Bf[0]), "+v"(Bf[1]), "+v"(Bf[2]), "+v"(Bf[3]),
                              "+v"(Bf[4]), "+v"(Bf[5]), "+v"(Bf[6]), "+v"(Bf[7]));

            // ---- off-chain inputs (ready before dot arrives) ----
            float xt = lane_bcast(xcur, tt);          // x_t (I=1: same for all h)
            float cb = fmaf(xt, wihC2, biasC2) + G;   // C2*(xpre_t) + G_{t-1}

            // ---- critical chain: fma -> exp2 -> add -> rcp -> fma ----
            float targ = fmaf(C2K, dot, cb);          // C2 * arg_t
            float e    = __builtin_amdgcn_exp2f(targ);
            float r    = __builtin_amdgcn_rcpf(1.0f + e);
            float cell = fmaf(-2.0f, r, 1.0f);        // tanh(arg)

            hbuf[lane] = (_Float16)cell;              // publish (same-wave, in-order)

            // ---- off-chain state updates (overlap the LDS round-trip) ----
            G = fmaf(ONE_MINUS_K, G, C2KK * dot);     // -> G_t
            h = fmaf(KBLEND, cell - h, h);            // h_t = h + K*(cell-h)
            *outp = h;                                // coalesced 256B/wave store
            outp += HDIM;

            // ---- A frags: 2x ds_read_b128, per-lane-group broadcast ----
            f16x8 a0 = *reinterpret_cast<const f16x8*>(hbB + gofs);        // c[g*8..]
            f16x8 a1 = *reinterpret_cast<const f16x8*>(hbB + 64 + gofs);   // c[32+g*8..]

            // ---- matvec via 8 MFMA (4 n-tiles x 2 k-tiles, f32 accum) ----
            f32x4 d0 = __builtin_amdgcn_mfma_f32_16x16x32_f16(a0, Bf[0], (f32x4){0,0,0,0}, 0, 0, 0);
            f32x4 d1 = __builtin_amdgcn_mfma_f32_16x16x32_f16(a0, Bf[2], (f32x4){0,0,0,0}, 0, 0, 0);
            f32x4 d2 = __builtin_amdgcn_mfma_f32_16x16x32_f16(a0, Bf[4], (f32x4){0,0,0,0}, 0, 0, 0);
            f32x4 d3 = __builtin_amdgcn_mfma_f32_16x16x32_f16(a0, Bf[6], (f32x4){0,0,0,0}, 0, 0, 0);
            d0 = __builtin_amdgcn_mfma_f32_16x16x32_f16(a1, Bf[1], d0, 0, 0, 0);
            d1 = __builtin_amdgcn_mfma_f32_16x16x32_f16(a1, Bf[3], d1, 0, 0, 0);
            d2 = __builtin_amdgcn_mfma_f32_16x16x32_f16(a1, Bf[5], d2, 0, 0, 0);
            d3 = __builtin_amdgcn_mfma_f32_16x16x32_f16(a1, Bf[7], d3, 0, 0, 0);

            // ---- select dot[lane]: D_{lane>>4}, col lane&15, any row (reg 0) ----
            float t01 = selLo ? d1[0] : d0[0];
            float t23 = selLo ? d3[0] : d2[0];
            dot = selHi ? t23 : t01;                  // dot_t
        }

        xcur = xnext;   // rotate x chunk (register, no LDS)
    }

    out_hlast[b * HDIM + lane] = h;
}

extern "C" void kernel_launch(void* const* d_in, const int* in_sizes, int n_in,
                              void* d_out, int out_size, void* d_ws, size_t ws_size,
                              hipStream_t stream) {
    const float* x   = (const float*)d_in[0];
    const float* Wih = (const float*)d_in[1];
    const float* Whh = (const float*)d_in[2];
    const float* bih = (const float*)d_in[3];
    const float* bhh = (const float*)d_in[4];

    float* out_states = (float*)d_out;
    float* out_hlast  = out_states + (size_t)BATCH * T_LEN * HDIM;

    rnn_delayline_kernel<<<dim3(BATCH), dim3(HDIM), 0, stream>>>(
        x, Wih, Whh, bih, bhh, out_states, out_hlast);
}